// Round 2
// baseline (1378.429 us; speedup 1.0000x reference)
//
#include <hip/hip_runtime.h>
#include <cstdint>
#include <cstddef>

#define NN 100000
#define NE 3200000
#define DD 512

typedef __attribute__((ext_vector_type(4))) float f32x4;
typedef __attribute__((ext_vector_type(8))) __bf16 bf16x8;
typedef __attribute__((ext_vector_type(8))) unsigned short u16x8;
typedef __attribute__((ext_vector_type(4))) unsigned short u16x4;

__device__ __forceinline__ unsigned short f2bf(float x) {
    unsigned u = __builtin_bit_cast(unsigned, x);
    u = (u + 0x7FFFu + ((u >> 16) & 1u)) >> 16;
    return (unsigned short)u;
}
__device__ __forceinline__ float bf2f(unsigned short x) {
    unsigned u = ((unsigned)x) << 16;
    return __builtin_bit_cast(float, u);
}

// ---- weight transpose: W[k][n] f32 -> Bt[n][k] bf16 (LDS tiled, coalesced both sides)
__global__ __launch_bounds__(256) void wtr_kernel(const float* __restrict__ W,
                                                  unsigned short* __restrict__ Bt) {
    __shared__ unsigned short tile[64][65];
    int t = threadIdx.x;
    int bn = blockIdx.x & 7;   // n tile
    int bk = blockIdx.x >> 3;  // k tile
    #pragma unroll
    for (int i = 0; i < 16; ++i) {
        int flat = i * 256 + t;
        int r = flat >> 6, c = flat & 63;  // r = k off, c = n off
        tile[r][c] = f2bf(W[(size_t)(bk * 64 + r) * DD + bn * 64 + c]);
    }
    __syncthreads();
    #pragma unroll
    for (int i = 0; i < 16; ++i) {
        int flat = i * 256 + t;
        int r = flat >> 6, c = flat & 63;  // r = n off, c = k off
        Bt[(size_t)(bn * 64 + r) * DD + bk * 64 + c] = tile[c][r];
    }
}

// ---- histogram of destination rows
__global__ __launch_bounds__(256) void hist_kernel(const int* __restrict__ rows,
                                                   int* __restrict__ cnt) {
    int i = blockIdx.x * 256 + threadIdx.x;
    if (i < NE) atomicAdd(&cnt[rows[i]], 1);
}

// ---- single-block exclusive scan over NN counters -> row_start[NN+1]
__global__ __launch_bounds__(1024) void scan_kernel(const int* __restrict__ cnt,
                                                    int* __restrict__ rs) {
    __shared__ int lds[1024];
    int t = threadIdx.x;
    const int per = (NN + 1023) / 1024;  // 98
    int b = t * per; if (b > NN) b = NN;
    int e = b + per; if (e > NN) e = NN;
    int s = 0;
    for (int i = b; i < e; ++i) s += cnt[i];
    lds[t] = s;
    __syncthreads();
    for (int off = 1; off < 1024; off <<= 1) {
        int u = (t >= off) ? lds[t - off] : 0;
        __syncthreads();
        lds[t] += u;
        __syncthreads();
    }
    int run = lds[t] - s;  // exclusive prefix of this thread's range
    for (int i = b; i < e; ++i) { rs[i] = run; run += cnt[i]; }
    if (t == 1023) rs[NN] = lds[1023];
}

// ---- scatter edges into CSR order: ed[pos] = (src_col, val_bits)
__global__ __launch_bounds__(256) void scatter_kernel(const int* __restrict__ rows,
                                                      const int* __restrict__ cols,
                                                      const float* __restrict__ vals,
                                                      const int* __restrict__ rs,
                                                      int* __restrict__ cur,
                                                      int2* __restrict__ ed) {
    int i = blockIdx.x * 256 + threadIdx.x;
    if (i < NE) {
        int r = rows[i];
        int p = rs[r] + atomicAdd(&cur[r], 1);
        ed[p] = make_int2(cols[i], __float_as_int(vals[i]));
    }
}

// ---- GEMM: support[m][n] = bf16( X[m][:] @ W[:][n] ), X fp32, W pre-transposed bf16
// 128x128 tile, BK=32, 4 waves (2x2), each wave 64x64 via 4x4 16x16x32 MFMA frags.
__global__ __launch_bounds__(256) void gemm_kernel(const float* __restrict__ A,
                                                   const unsigned short* __restrict__ Bt,
                                                   unsigned short* __restrict__ S) {
    __shared__ unsigned short sA[128 * 40];  // [row][k] pad to 40 (80B stride, 5 coprime 8)
    __shared__ unsigned short sB[128 * 40];  // [col][k]
    const int tid = threadIdx.x;
    const int lane = tid & 63;
    const int w = tid >> 6;
    const int wm = w >> 1, wn = w & 1;
    const int row0 = blockIdx.x * 128;
    const int n0 = blockIdx.y * 128;
    const int kg = lane >> 4;
    const int r16 = lane & 15;

    f32x4 acc[4][4] = {};

    for (int kt = 0; kt < DD / 32; ++kt) {
        const int k0 = kt * 32;
        __syncthreads();
        // stage A tile (128x32 fp32 -> bf16), 4 float4 per thread
        #pragma unroll
        for (int i = 0; i < 4; ++i) {
            int f = i * 256 + tid;   // float4 index, 1024 total
            int r = f >> 3;          // row 0..127
            int kq = f & 7;          // k quad
            int gr = row0 + r;
            float4 v = make_float4(0.f, 0.f, 0.f, 0.f);
            if (gr < NN) v = *reinterpret_cast<const float4*>(&A[(size_t)gr * DD + k0 + kq * 4]);
            u16x4 bv;
            bv[0] = f2bf(v.x); bv[1] = f2bf(v.y); bv[2] = f2bf(v.z); bv[3] = f2bf(v.w);
            *reinterpret_cast<u16x4*>(&sA[r * 40 + kq * 4]) = bv;
        }
        // stage B tile (128 cols x 32 k bf16), 2 x 16B per thread
        #pragma unroll
        for (int i = 0; i < 2; ++i) {
            int c = i * 256 + tid;   // 16B chunk index, 512 total
            int n = c >> 2;          // col 0..127
            int kq = c & 3;          // 8-elem k group
            u16x8 v = *reinterpret_cast<const u16x8*>(&Bt[(size_t)(n0 + n) * DD + k0 + kq * 8]);
            *reinterpret_cast<u16x8*>(&sB[n * 40 + kq * 8]) = v;
        }
        __syncthreads();
        bf16x8 af[4], bfv[4];
        #pragma unroll
        for (int mi = 0; mi < 4; ++mi)
            af[mi] = *reinterpret_cast<const bf16x8*>(&sA[(wm * 64 + mi * 16 + r16) * 40 + kg * 8]);
        #pragma unroll
        for (int ni = 0; ni < 4; ++ni)
            bfv[ni] = *reinterpret_cast<const bf16x8*>(&sB[(wn * 64 + ni * 16 + r16) * 40 + kg * 8]);
        #pragma unroll
        for (int mi = 0; mi < 4; ++mi)
            #pragma unroll
            for (int ni = 0; ni < 4; ++ni)
                acc[mi][ni] = __builtin_amdgcn_mfma_f32_16x16x32_bf16(af[mi], bfv[ni], acc[mi][ni], 0, 0, 0);
    }

    // C/D layout: col = lane&15, row = (lane>>4)*4 + reg
    const int cg = lane >> 4;
    const int cl = lane & 15;
    #pragma unroll
    for (int mi = 0; mi < 4; ++mi) {
        #pragma unroll
        for (int ni = 0; ni < 4; ++ni) {
            #pragma unroll
            for (int r = 0; r < 4; ++r) {
                int row = row0 + wm * 64 + mi * 16 + cg * 4 + r;
                if (row < NN)
                    S[(size_t)row * DD + n0 + wn * 64 + ni * 16 + cl] = f2bf(acc[mi][ni][r]);
            }
        }
    }
}

// ---- aggregate: one wave per destination node; each edge = one coalesced 1KB row gather
__global__ __launch_bounds__(256) void agg_kernel(const unsigned short* __restrict__ S,
                                                  const int2* __restrict__ ed,
                                                  const int* __restrict__ rs,
                                                  float* __restrict__ out) {
    int node = blockIdx.x * 4 + (threadIdx.x >> 6);
    if (node >= NN) return;
    int lane = threadIdx.x & 63;
    int beg = rs[node], end = rs[node + 1];
    float acc[8] = {0.f, 0.f, 0.f, 0.f, 0.f, 0.f, 0.f, 0.f};
    int e = beg;
    for (; e + 4 <= end; e += 4) {
        int2 e0 = ed[e], e1 = ed[e + 1], e2 = ed[e + 2], e3 = ed[e + 3];
        u16x8 s0 = *reinterpret_cast<const u16x8*>(&S[(size_t)e0.x * DD + lane * 8]);
        u16x8 s1 = *reinterpret_cast<const u16x8*>(&S[(size_t)e1.x * DD + lane * 8]);
        u16x8 s2 = *reinterpret_cast<const u16x8*>(&S[(size_t)e2.x * DD + lane * 8]);
        u16x8 s3 = *reinterpret_cast<const u16x8*>(&S[(size_t)e3.x * DD + lane * 8]);
        float v0 = __int_as_float(e0.y), v1 = __int_as_float(e1.y);
        float v2 = __int_as_float(e2.y), v3 = __int_as_float(e3.y);
        #pragma unroll
        for (int j = 0; j < 8; ++j) {
            acc[j] += v0 * bf2f(s0[j]);
            acc[j] += v1 * bf2f(s1[j]);
            acc[j] += v2 * bf2f(s2[j]);
            acc[j] += v3 * bf2f(s3[j]);
        }
    }
    for (; e < end; ++e) {
        int2 e0 = ed[e];
        u16x8 s0 = *reinterpret_cast<const u16x8*>(&S[(size_t)e0.x * DD + lane * 8]);
        float v0 = __int_as_float(e0.y);
        #pragma unroll
        for (int j = 0; j < 8; ++j) acc[j] += v0 * bf2f(s0[j]);
    }
    f32x4 o0, o1;
    #pragma unroll
    for (int j = 0; j < 4; ++j) {
        o0[j] = fmaxf(acc[j], 0.f);
        o1[j] = fmaxf(acc[4 + j], 0.f);
    }
    size_t base = (size_t)node * DD + (size_t)lane * 8;
    *reinterpret_cast<f32x4*>(&out[base]) = o0;
    *reinterpret_cast<f32x4*>(&out[base + 4]) = o1;
}

extern "C" void kernel_launch(void* const* d_in, const int* in_sizes, int n_in,
                              void* d_out, int out_size, void* d_ws, size_t ws_size,
                              hipStream_t stream) {
    const float* feat = (const float*)d_in[0];
    const float* wgt  = (const float*)d_in[1];
    const int*   rows = (const int*)d_in[2];
    const int*   cols = (const int*)d_in[3];
    const float* vals = (const float*)d_in[4];
    float* out = (float*)d_out;

    char* ws = (char*)d_ws;
    size_t off = 0;
    auto alloc = [&](size_t bytes) -> void* {
        void* p = (void*)(ws + off);
        off += (bytes + 255) & ~(size_t)255;
        return p;
    };
    unsigned short* support = (unsigned short*)alloc((size_t)NN * DD * 2);  // 102.4 MB
    unsigned short* Bt      = (unsigned short*)alloc((size_t)DD * DD * 2);  // 0.5 MB
    int* cnt  = (int*)alloc((size_t)NN * 4);
    int* rsv  = (int*)alloc((size_t)(NN + 1) * 4);
    int* cur  = (int*)alloc((size_t)NN * 4);
    int2* ed  = (int2*)alloc((size_t)NE * 8);                               // 25.6 MB

    hipMemsetAsync(cnt, 0, (size_t)NN * 4, stream);
    hipMemsetAsync(cur, 0, (size_t)NN * 4, stream);

    wtr_kernel<<<64, 256, 0, stream>>>(wgt, Bt);
    hist_kernel<<<(NE + 255) / 256, 256, 0, stream>>>(rows, cnt);
    scan_kernel<<<1, 1024, 0, stream>>>(cnt, rsv);
    scatter_kernel<<<(NE + 255) / 256, 256, 0, stream>>>(rows, cols, vals, rsv, cur, ed);
    gemm_kernel<<<dim3((NN + 127) / 128, DD / 128), 256, 0, stream>>>(feat, Bt, support);
    agg_kernel<<<(NN + 3) / 4, 256, 0, stream>>>(support, ed, rsv, out);
}